// Round 9
// baseline (535.180 us; speedup 1.0000x reference)
//
#include <hip/hip_runtime.h>

#define N_NODES 100000
#define N_EDGES 3200000
#define NGRAPH 512
#define NCLASS 6
#define BN_EPS 1e-5f

#define BSHIFT 8
#define NBUCK 391          // ceil(100000 / 256)
#define CHUNK 8192         // edges per block in bucket passes
#define EB 391             // ceil(N_EDGES / CHUNK)
#define NBLK_NODE 391      // ceil(N_NODES / 256)
#define FUSG 3125          // k_fused grid: 2 waves/block x 16 nodes = 32 nodes/block
#define CAST_B 6250        // N_NODES*64/4/256 exactly
#define BSMAX 12032        // k_bsort LDS capacity (mean 8192 + 42 sigma)
#define NBANK 64           // BN accumulator banks (R14 lesson: spread the RMW chains)

typedef unsigned short u16;
typedef unsigned int u32;
typedef __attribute__((ext_vector_type(8))) short bf16x8;
typedef __attribute__((ext_vector_type(4))) float f32x4;
typedef __attribute__((ext_vector_type(2))) float f32x2;
typedef __attribute__((ext_vector_type(4))) u16 u16x4;

__device__ __forceinline__ float bflo(u32 b) {
    u32 t = b << 16; return __builtin_bit_cast(float, t);
}
__device__ __forceinline__ float bfhi(u32 b) {
    u32 t = b & 0xffff0000u; return __builtin_bit_cast(float, t);
}
__device__ __forceinline__ f32x2 bfpair(u32 b) {
    return (f32x2){bflo(b), bfhi(b)};
}
__device__ __forceinline__ u16 f2bf(float f) {   // round-to-nearest-even
    u32 u = __builtin_bit_cast(u32, f);
    return (u16)((u + 0x7fffu + ((u >> 16) & 1u)) >> 16);
}

// ---------------- fused setup: cast | weight-prep+bank-zero | edge hist | gstart --------
// R19: nt loads/stores on all read-once / write-once streams (x, xb, dst).
__global__ void k_setup(const float* __restrict__ x, u16* __restrict__ xb,
                        const float* __restrict__ W10, const float* __restrict__ W20,
                        const float* __restrict__ W11, const float* __restrict__ W21,
                        const float* __restrict__ W12, const float* __restrict__ W22,
                        u16* __restrict__ Wtg, float* __restrict__ banks,
                        const int* __restrict__ dst, const int* __restrict__ batch,
                        int* __restrict__ blockhist, int* __restrict__ gstart,
                        int* __restrict__ rowstart) {
    __shared__ int hist[NBUCK];
    int b = blockIdx.x;
    int t = threadIdx.x;
    if (b < CAST_B) {
        int base = (b * 256 + t) * 4;
        f32x4 v = __builtin_nontemporal_load((const f32x4*)(x + base));
        u16x4 o = {f2bf(v.x), f2bf(v.y), f2bf(v.z), f2bf(v.w)};
        __builtin_nontemporal_store(o, (u16x4*)(xb + base));
    } else if (b < CAST_B + 97) {
        int bb = b - CAST_B;
        if (bb < 96) {
            int e = bb * 256 + t;          // < 24576 = 6 * 4096
            int mat = e >> 12;
            int i = e & 4095;
            const float* s = (mat == 0) ? W10 : (mat == 1) ? W20 : (mat == 2) ? W11
                           : (mat == 3) ? W21 : (mat == 4) ? W12 : W22;
            float v = s[i];
            int k = i >> 6, c = i & 63;
            Wtg[mat * 4608 + c * 72 + k] = f2bf(v);
        } else {
            // zero all 4 layers' BN banks: 4*64*128 floats = 8192 uint4
            uint4 z = make_uint4(0, 0, 0, 0);
            for (int i = t; i < 8192; i += 256) ((uint4*)banks)[i] = z;
            if (t == 0) rowstart[N_NODES] = N_EDGES;
        }
    } else if (b < CAST_B + 97 + EB) {
        int be = b - (CAST_B + 97);
        long e0 = (long)be * CHUNK;
        for (int i = t; i < NBUCK; i += 256) hist[i] = 0;
        __syncthreads();
        for (int i = t; i < CHUNK; i += 256) {
            long e = e0 + i;
            if (e < N_EDGES)
                atomicAdd(&hist[__builtin_nontemporal_load(dst + e) >> BSHIFT], 1);
        }
        __syncthreads();
        for (int i = t; i < NBUCK; i += 256) blockhist[be * NBUCK + i] = hist[i];
    } else {
        int i = (b - (CAST_B + 97 + EB)) * 256 + t;
        if (i < N_NODES) {
            int bi = batch[i];
            int bp = (i == 0) ? -1 : batch[i - 1];
            for (int g = bp + 1; g <= bi; ++g) gstart[g] = i;
            if (i == N_NODES - 1)
                for (int g = bi + 1; g <= NGRAPH; ++g) gstart[g] = N_NODES;
        }
    }
}

// one block per bucket k: exclusive-scan blockhist column k (in place) + total.
__global__ void k_scan_cols(int* __restrict__ blockhist, int* __restrict__ colsum) {
    __shared__ int sh[512];
    int k = blockIdx.x;
    int t = threadIdx.x;
    int v = (t < EB) ? blockhist[t * NBUCK + k] : 0;
    sh[t] = v;
    __syncthreads();
    for (int off = 1; off < 512; off <<= 1) {
        int x = (t >= off) ? sh[t - off] : 0;
        __syncthreads();
        sh[t] += x;
        __syncthreads();
    }
    if (t < EB) blockhist[t * NBUCK + k] = sh[t] - v;
    if (t == 511) colsum[k] = sh[511];
}

// LDS-staged bucket scatter (R18 structure). R19: nt on src/dst loads + pairs
// stores (all read/write-once streams -- keep them out of L2).
__global__ __launch_bounds__(512) void k_bscatter(
    const int* __restrict__ src, const int* __restrict__ dst,
    const int* __restrict__ colsum, const int* __restrict__ blockhist,
    int* __restrict__ pairs, int* __restrict__ bstart_g) {
    __shared__ int sh[512];
    __shared__ int bstart_s[NBUCK];
    __shared__ int cur[NBUCK];
    __shared__ int gbase[NBUCK];
    __shared__ u32 sorted[CHUNK];
    __shared__ u16 kbuf[CHUNK];
    int t = threadIdx.x;
    int b = blockIdx.x;
    long e0 = (long)b * CHUNK;
    // issue all global reads up front (colsum + my blockhist row + next row)
    int v = (t < NBUCK) ? colsum[t] : 0;
    int myrow = (t < NBUCK) ? blockhist[b * NBUCK + t] : 0;
    int nxt = (t < NBUCK) ? ((b < EB - 1) ? blockhist[(b + 1) * NBUCK + t] : v) : 0;
    int own = nxt - myrow;                 // this chunk's count for bucket t
    sh[t] = v;
    __syncthreads();
    for (int off = 1; off < 512; off <<= 1) {
        int x = (t >= off) ? sh[t - off] : 0;
        __syncthreads();
        sh[t] += x;
        __syncthreads();
    }
    if (t < NBUCK) bstart_s[t] = sh[t] - v;
    if (b == 0) {
        if (t < NBUCK) bstart_g[t] = sh[t] - v;
        if (t == 0) bstart_g[NBUCK] = N_EDGES;
    }
    __syncthreads();
    sh[t] = (t < NBUCK) ? own : 0;
    __syncthreads();
    for (int off = 1; off < 512; off <<= 1) {
        int x = (t >= off) ? sh[t - off] : 0;
        __syncthreads();
        sh[t] += x;
        __syncthreads();
    }
    if (t < NBUCK) {
        int excl = sh[t] - own;
        cur[t] = excl;
        gbase[t] = bstart_s[t] + myrow - excl;
    }
    __syncthreads();
    for (int i = t; i < CHUNK; i += 512) {
        long e = e0 + i;
        if (e < N_EDGES) {
            int d = __builtin_nontemporal_load(dst + e);
            int s = __builtin_nontemporal_load(src + e);
            int k = d >> BSHIFT;
            int r = atomicAdd(&cur[k], 1);
            sorted[r] = ((u32)s << 8) | (u32)(d & 255);
            kbuf[r] = (u16)k;
        }
    }
    __syncthreads();
    int tot = (int)min((long)CHUNK, (long)N_EDGES - e0);
    for (int i = t; i < tot; i += 512)
        __builtin_nontemporal_store((int)sorted[i], &pairs[gbase[kbuf[i]] + i]);
}

// per-bucket fine counting sort (R18 structure). R19: nt pairs loads + esrc
// stores (read-once / written-then-read-3-kernels-later).
__global__ __launch_bounds__(512) void k_bsort(
    const int* __restrict__ pairs, const int* __restrict__ bstart_g,
    int* __restrict__ rowstart, int* __restrict__ esrc) {
    __shared__ int sh[256];
    __shared__ int deg[256];
    __shared__ int cur[256];
    __shared__ u32 ssrc[BSMAX];
    int b = blockIdx.x;
    int t = threadIdx.x;
    int p0 = bstart_g[b];
    int p1 = bstart_g[b + 1];
    int n = p1 - p0;
    if (t < 256) deg[t] = 0;
    __syncthreads();
    for (int i = p0 + t; i < p1; i += 512)
        atomicAdd(&deg[__builtin_nontemporal_load(pairs + i) & 255], 1);
    __syncthreads();
    if (t < 256) sh[t] = deg[t];
    __syncthreads();
    for (int off = 1; off < 256; off <<= 1) {
        int x = (t >= off && t < 256) ? sh[t - off] : 0;
        __syncthreads();
        if (t < 256) sh[t] += x;
        __syncthreads();
    }
    if (t < 256) {
        int excl = sh[t] - deg[t];
        cur[t] = excl;
        int node = (b << BSHIFT) + t;
        if (node < N_NODES) rowstart[node] = p0 + excl;
    }
    __syncthreads();
    if (n <= BSMAX) {
        for (int i = p0 + t; i < p1; i += 512) {
            u32 pr = (u32)__builtin_nontemporal_load(pairs + i);
            int r = atomicAdd(&cur[pr & 255], 1);
            ssrc[r] = pr >> 8;
        }
        __syncthreads();
        for (int i = t; i < n; i += 512)
            __builtin_nontemporal_store((int)ssrc[i], &esrc[p0 + i]);
    } else {   // statistical impossibility; correctness fallback
        for (int i = p0 + t; i < p1; i += 512) {
            u32 pr = (u32)pairs[i];
            int r = atomicAdd(&cur[pr & 255], 1);
            esrc[p0 + r] = (int)(pr >> 8);
        }
    }
}

// ---------------- fused GIN layer: per-WAVE agg -> LDS -> MFMA ----------------
// Phase A/B structure VERBATIM R10 (proven; every restructuring lost). R19:
// memory-op annotation only -- nt loads for esrc (read-once; stop evicting hin
// gather lines from L2), nt stores for C (kill write-allocate FETCH; cross-XCD
// reuse next layer is only ~1/8). hin gather + self rows stay CACHED (deg~32
// reuse). BN banks per R17.
__global__ __launch_bounds__(128, 5) void k_fused(
    const u16* __restrict__ hin, const float* __restrict__ bank_in,
    const float* __restrict__ gbn, const float* __restrict__ bebn, int raw,
    const float* __restrict__ epsp, const int* __restrict__ rowstart,
    const int* __restrict__ esrc, const u16* __restrict__ Wt,
    const float* __restrict__ b1, const float* __restrict__ b2,
    u16* __restrict__ C, float* __restrict__ bank_out) {
    __shared__ __align__(16) u16 Ain[2][16 * 72];
    __shared__ __align__(16) u16 Hs[2][16 * 72];
    __shared__ float bnl[128];
    int tid = threadIdx.x;
    int lane = tid & 63;
    int wid = tid >> 6;
    int r0 = blockIdx.x * 32 + wid * 16;

    // ---- BN prologue: column-reduce banks -> LDS -> per-thread scale/shift ----
    if (!raw) {
        float s = 0.f;
        #pragma unroll 8
        for (int b = 0; b < NBANK; ++b) s += bank_in[b * 128 + tid];
        bnl[tid] = s;
    }
    __syncthreads();

    int grp = lane >> 3;
    int f0 = 8 * (lane & 7);
    float epsv = 1.0f + epsp[0];
    float sc[8], sh[8];
    if (raw) {
        #pragma unroll
        for (int k = 0; k < 8; ++k) { sc[k] = 1.0f; sh[k] = 0.0f; }
    } else {
        #pragma unroll
        for (int k = 0; k < 8; ++k) {
            int f = f0 + k;
            float S = bnl[f];
            float Q = bnl[64 + f];
            float mu = S * (1.0f / (float)N_NODES);
            float var = fmaxf(Q * (1.0f / (float)N_NODES) - mu * mu, 0.f);
            float s = gbn[f] * rsqrtf(var + BN_EPS);
            sc[k] = s;
            sh[k] = bebn[f] - mu * s;
        }
    }

    // ---- phase A: aggregate 16 nodes (R10 body) ----
    for (int t = 0; t < 16; ++t) {
        int node = r0 + t;
        u32* arow = (u32*)&Ain[wid][0] + t * 36 + (lane & 7) * 4;
        if (node < N_NODES) {
            f32x2 ac0 = {0.f, 0.f}, ac1 = {0.f, 0.f}, ac2 = {0.f, 0.f}, ac3 = {0.f, 0.f};
            int e0 = rowstart[node], e1 = rowstart[node + 1];
            for (int i = e0; i < e1; i += 64) {
                int cnt = min(e1 - i, 64);
                int src = (lane < cnt) ? __builtin_nontemporal_load(esrc + i + lane) : 0;
                int j = 0;
                for (; j + 16 <= cnt; j += 16) {
                    int a = __shfl(src, j + grp);
                    int b = __shfl(src, j + 8 + grp);
                    uint4 va = *(const uint4*)(hin + (size_t)a * 64 + f0);
                    uint4 vb = *(const uint4*)(hin + (size_t)b * 64 + f0);
                    ac0 += bfpair(va.x); ac1 += bfpair(va.y);
                    ac2 += bfpair(va.z); ac3 += bfpair(va.w);
                    ac0 += bfpair(vb.x); ac1 += bfpair(vb.y);
                    ac2 += bfpair(vb.z); ac3 += bfpair(vb.w);
                }
                if (j + 8 <= cnt) {
                    int a = __shfl(src, j + grp);
                    uint4 va = *(const uint4*)(hin + (size_t)a * 64 + f0);
                    ac0 += bfpair(va.x); ac1 += bfpair(va.y);
                    ac2 += bfpair(va.z); ac3 += bfpair(va.w);
                    j += 8;
                }
                if (j < cnt) {   // clamp src (all lanes active), gate accumulate
                    int jj = j + grp;
                    int a = __shfl(src, (jj < cnt) ? jj : (cnt - 1));
                    uint4 va = *(const uint4*)(hin + (size_t)a * 64 + f0);
                    if (jj < cnt) {
                        ac0 += bfpair(va.x); ac1 += bfpair(va.y);
                        ac2 += bfpair(va.z); ac3 += bfpair(va.w);
                    }
                }
            }
            float acc[8] = {ac0.x, ac0.y, ac1.x, ac1.y, ac2.x, ac2.y, ac3.x, ac3.y};
            #pragma unroll
            for (int k = 0; k < 8; ++k) {
                acc[k] += __shfl_xor(acc[k], 8);
                acc[k] += __shfl_xor(acc[k], 16);
                acc[k] += __shfl_xor(acc[k], 32);
            }
            float deg = (float)(e1 - e0);
            uint4 sb = *(const uint4*)(hin + (size_t)node * 64 + f0);
            float self[8] = {bflo(sb.x), bfhi(sb.x), bflo(sb.y), bfhi(sb.y),
                             bflo(sb.z), bfhi(sb.z), bflo(sb.w), bfhi(sb.w)};
            if (grp == 0) {
                u32 pk[4];
                #pragma unroll
                for (int k = 0; k < 4; ++k) {
                    float oa = sc[2 * k] * (acc[2 * k] + epsv * self[2 * k]) +
                               (deg + epsv) * sh[2 * k];
                    float ob = sc[2 * k + 1] * (acc[2 * k + 1] + epsv * self[2 * k + 1]) +
                               (deg + epsv) * sh[2 * k + 1];
                    pk[k] = (u32)f2bf(oa) | ((u32)f2bf(ob) << 16);
                }
                *(uint4*)arow = make_uint4(pk[0], pk[1], pk[2], pk[3]);
            }
        } else if (grp == 0) {
            *(uint4*)arow = make_uint4(0, 0, 0, 0);
        }
    }
    // no barrier: phase B reads only this wave's Ain tile (in-order DS per wave)

    // ---- phase B: MFMA MLP on the wave's 16-row tile ----
    const u16* Wt2 = Wt + 4608;
    int m = lane & 15;
    int q = lane >> 4;

    bf16x8 a0 = *(const bf16x8*)(&Ain[wid][m * 72 + q * 8]);
    bf16x8 a1 = *(const bf16x8*)(&Ain[wid][m * 72 + 32 + q * 8]);
    f32x4 acc[4];
    #pragma unroll
    for (int c = 0; c < 4; ++c) {
        acc[c] = (f32x4){0.f, 0.f, 0.f, 0.f};
        bf16x8 bA = *(const bf16x8*)(Wt + (c * 16 + m) * 72 + q * 8);
        bf16x8 bB = *(const bf16x8*)(Wt + (c * 16 + m) * 72 + 32 + q * 8);
        acc[c] = __builtin_amdgcn_mfma_f32_16x16x32_bf16(a0, bA, acc[c], 0, 0, 0);
        acc[c] = __builtin_amdgcn_mfma_f32_16x16x32_bf16(a1, bB, acc[c], 0, 0, 0);
    }
    #pragma unroll
    for (int c = 0; c < 4; ++c) {
        int col = c * 16 + m;
        float bb = b1[col];
        #pragma unroll
        for (int r = 0; r < 4; ++r)
            Hs[wid][(q * 4 + r) * 72 + col] = f2bf(fmaxf(acc[c][r] + bb, 0.f));
    }
    bf16x8 h0 = *(const bf16x8*)(&Hs[wid][m * 72 + q * 8]);
    bf16x8 h1 = *(const bf16x8*)(&Hs[wid][m * 72 + 32 + q * 8]);
    f32x4 acc2[4];
    #pragma unroll
    for (int c = 0; c < 4; ++c) {
        acc2[c] = (f32x4){0.f, 0.f, 0.f, 0.f};
        bf16x8 bA = *(const bf16x8*)(Wt2 + (c * 16 + m) * 72 + q * 8);
        bf16x8 bB = *(const bf16x8*)(Wt2 + (c * 16 + m) * 72 + 32 + q * 8);
        acc2[c] = __builtin_amdgcn_mfma_f32_16x16x32_bf16(h0, bA, acc2[c], 0, 0, 0);
        acc2[c] = __builtin_amdgcn_mfma_f32_16x16x32_bf16(h1, bB, acc2[c], 0, 0, 0);
    }
    float* bo = bank_out + (size_t)(((blockIdx.x << 1) | wid) & (NBANK - 1)) * 128;
    #pragma unroll
    for (int c = 0; c < 4; ++c) {
        int col = c * 16 + m;
        float bb = b2[col];
        float psum = 0.f, psq = 0.f;
        #pragma unroll
        for (int r = 0; r < 4; ++r) {
            int rg = r0 + q * 4 + r;
            if (rg < N_NODES) {
                float o = fmaxf(acc2[c][r] + bb, 0.f);
                __builtin_nontemporal_store(f2bf(o), &C[(size_t)rg * 64 + col]);
                psum += o;
                psq += o * o;
            }
        }
        psum += __shfl_xor(psum, 16);
        psum += __shfl_xor(psum, 32);
        psq += __shfl_xor(psq, 16);
        psq += __shfl_xor(psq, 32);
        if (q == 0) {
            atomicAdd(&bo[col], psum);          // fire-and-forget, spread banks
            atomicAdd(&bo[64 + col], psq);
        }
    }
}

// ---------------- pooling + FC + log_softmax ----------------
__global__ void k_pool(const u16* __restrict__ h, const float* __restrict__ bank_in,
                       const float* __restrict__ gbn, const float* __restrict__ bebn,
                       const int* __restrict__ gstart, const float* __restrict__ wfc,
                       const float* __restrict__ bfc, float* __restrict__ out) {
    __shared__ float smean[2][128];
    __shared__ float smax[2][128];
    __shared__ float lg[2][8];
    __shared__ float bnl[128];
    int tid = threadIdx.x;
    int lane = tid & 63;
    int w = tid >> 6;
    int gi = w >> 1;
    int part = w & 1;
    int gr = blockIdx.x * 2 + gi;
    int half = lane >> 5;
    int li = lane & 31;
    int f0 = 2 * li;

    if (tid < 128) {
        float s = 0.f;
        #pragma unroll 8
        for (int b = 0; b < NBANK; ++b) s += bank_in[b * 128 + tid];
        bnl[tid] = s;
    }
    __syncthreads();
    float sc0, sc1, sh0, sh1;
    {
        float S0 = bnl[f0], Q0 = bnl[64 + f0];
        float S1 = bnl[f0 + 1], Q1 = bnl[64 + f0 + 1];
        float mu0 = S0 * (1.0f / (float)N_NODES);
        float mu1 = S1 * (1.0f / (float)N_NODES);
        float v0 = fmaxf(Q0 * (1.0f / (float)N_NODES) - mu0 * mu0, 0.f);
        float v1 = fmaxf(Q1 * (1.0f / (float)N_NODES) - mu1 * mu1, 0.f);
        sc0 = gbn[f0] * rsqrtf(v0 + BN_EPS);
        sc1 = gbn[f0 + 1] * rsqrtf(v1 + BN_EPS);
        sh0 = bebn[f0] - mu0 * sc0;
        sh1 = bebn[f0 + 1] - mu1 * sc1;
    }
    int s0n = gstart[gr], s1n = gstart[gr + 1];
    int cnt = s1n - s0n;
    int mid = s0n + (cnt >> 1);
    int a = part ? mid : s0n;
    int b = part ? s1n : mid;
    float sum0 = 0.f, sum1 = 0.f, mx0 = -3.4e38f, mx1 = -3.4e38f;
    for (int n = a + half; n < b; n += 2) {
        u32 bits = __builtin_nontemporal_load((const u32*)(h + (size_t)n * 64 + f0));
        float x0 = fmaf(bflo(bits), sc0, sh0);
        float x1 = fmaf(bfhi(bits), sc1, sh1);
        sum0 += x0; sum1 += x1;
        mx0 = fmaxf(mx0, x0); mx1 = fmaxf(mx1, x1);
    }
    sum0 += __shfl_xor(sum0, 32);
    sum1 += __shfl_xor(sum1, 32);
    mx0 = fmaxf(mx0, __shfl_xor(mx0, 32));
    mx1 = fmaxf(mx1, __shfl_xor(mx1, 32));
    if (half == 0 && part == 0) {
        smean[gi][f0] = sum0; smean[gi][f0 + 1] = sum1;
        smax[gi][f0] = mx0;   smax[gi][f0 + 1] = mx1;
    }
    __syncthreads();
    if (half == 0 && part == 1) {
        float m0 = fmaxf(smax[gi][f0], mx0), m1 = fmaxf(smax[gi][f0 + 1], mx1);
        float t0 = smean[gi][f0] + sum0, t1 = smean[gi][f0 + 1] + sum1;
        float fc = fmaxf((float)cnt, 1.f);
        smean[gi][f0] = t0 / fc;
        smean[gi][f0 + 1] = t1 / fc;
        smax[gi][f0] = (cnt > 0) ? m0 : 0.f;
        smax[gi][f0 + 1] = (cnt > 0) ? m1 : 0.f;
    }
    __syncthreads();
    if (part == 0 && lane < NCLASS) {
        float acc = bfc[lane];
        for (int j = 0; j < 64; ++j) acc = fmaf(smean[gi][j], wfc[j * NCLASS + lane], acc);
        for (int j = 0; j < 64; ++j) acc = fmaf(smax[gi][j], wfc[(64 + j) * NCLASS + lane], acc);
        lg[gi][lane] = acc;
    }
    __syncthreads();
    if (part == 0 && lane < NCLASS) {
        float mm = -3.4e38f;
        for (int c = 0; c < NCLASS; ++c) mm = fmaxf(mm, lg[gi][c]);
        float se = 0.f;
        for (int c = 0; c < NCLASS; ++c) se += expf(lg[gi][c] - mm);
        out[gr * NCLASS + lane] = lg[gi][lane] - mm - logf(se);
    }
}

// ---------------- launch ----------------

extern "C" void kernel_launch(void* const* d_in, const int* in_sizes, int n_in,
                              void* d_out, int out_size, void* d_ws, size_t ws_size,
                              hipStream_t stream) {
    const float* x = (const float*)d_in[0];
    const int* ei = (const int*)d_in[1];
    const int* batch = (const int*)d_in[2];
    const int* esrc_in = ei;
    const int* edst_in = ei + N_EDGES;

    const float* ba[4] = {(const float*)d_in[4], (const float*)d_in[8],
                          (const float*)d_in[12], (const float*)d_in[12]};
    const float* bb[4] = {(const float*)d_in[6], (const float*)d_in[10],
                          (const float*)d_in[14], (const float*)d_in[14]};
    const float* epsv[4] = {(const float*)d_in[15], (const float*)d_in[18],
                            (const float*)d_in[21], (const float*)d_in[24]};
    const float* gg[4] = {(const float*)d_in[16], (const float*)d_in[19],
                          (const float*)d_in[22], (const float*)d_in[25]};
    const float* bee[4] = {(const float*)d_in[17], (const float*)d_in[20],
                           (const float*)d_in[23], (const float*)d_in[26]};
    const float* wfc = (const float*)d_in[27];
    const float* bfc = (const float*)d_in[28];
    float* out = (float*)d_out;

    char* ws = (char*)d_ws;
    int* pairs = (int*)(ws + 0);               // 12,800,000 (dead after k_bsort)
    u16* bufA = (u16*)(ws + 0);                // alias of pairs (first write: L1)
    int* esrc = (int*)(ws + 12800000);         // 12,800,000
    u16* xb = (u16*)(ws + 25600000);           // 12,800,000
    u16* bufB = (u16*)(ws + 38400000);         // 12,800,000
    int* rowstart = (int*)(ws + 51200000);     // 400,128
    int* blockhist = (int*)(ws + 51600128);    // 612,352 (padded)
    int* colsum = (int*)(ws + 52212480);       // 2,048
    int* gstart = (int*)(ws + 52214528);       // 2,560
    float* banks = (float*)(ws + 52217088);    // 4 layers x 64 banks x 128 f32 = 131,072
    u16* Wtg = (u16*)(ws + 52348160);          // 55,296
    int* bstart_g = (int*)(ws + 52403456);     // 392 ints -> 2,048
    // total: 52,405,504 bytes; no memsets needed

    k_setup<<<CAST_B + 97 + EB + NBLK_NODE, 256, 0, stream>>>(
        x, xb, (const float*)d_in[3], (const float*)d_in[5], (const float*)d_in[7],
        (const float*)d_in[9], (const float*)d_in[11], (const float*)d_in[13],
        Wtg, banks, edst_in, batch, blockhist, gstart, rowstart);
    k_scan_cols<<<NBUCK, 512, 0, stream>>>(blockhist, colsum);
    k_bscatter<<<EB, 512, 0, stream>>>(esrc_in, edst_in, colsum, blockhist, pairs,
                                       bstart_g);
    k_bsort<<<NBUCK, 512, 0, stream>>>(pairs, bstart_g, rowstart, esrc);

    // ping-pong: L0 xb->B, L1 B->A, L2 A->B, L3 B->A; pool reads A
    const u16* hb[4] = {xb, bufB, bufA, bufB};
    u16* cb[4] = {bufB, bufA, bufB, bufA};
    for (int L = 0; L < 4; ++L) {
        const u16* wt = Wtg + (size_t)((L < 2) ? L : 2) * 9216;
        const float* bin = (L == 0) ? banks : banks + (size_t)(L - 1) * NBANK * 128;
        const float* gprev = (L == 0) ? gg[0] : gg[L - 1];
        const float* beprev = (L == 0) ? bee[0] : bee[L - 1];
        k_fused<<<FUSG, 128, 0, stream>>>(hb[L], bin, gprev, beprev, (L == 0) ? 1 : 0,
                                          epsv[L], rowstart, esrc, wt, ba[L], bb[L],
                                          cb[L], banks + (size_t)L * NBANK * 128);
    }

    k_pool<<<NGRAPH / 2, 256, 0, stream>>>(bufA, banks + (size_t)3 * NBANK * 128,
                                           gg[3], bee[3], gstart, wfc, bfc, out);
}

// Round 10
// 483.486 us; speedup vs baseline: 1.1069x; 1.1069x over previous
//
#include <hip/hip_runtime.h>

#define N_NODES 100000
#define N_EDGES 3200000
#define NGRAPH 512
#define NCLASS 6
#define BN_EPS 1e-5f

#define BSHIFT 8
#define NBUCK 391          // ceil(100000 / 256)
#define CHUNK 8192         // edges per block in bucket passes
#define EB 391             // ceil(N_EDGES / CHUNK)
#define NBLK_NODE 391      // ceil(N_NODES / 256)
#define FUSG 3125          // k_fused grid: 2 waves/block x 16 nodes = 32 nodes/block
#define CAST_B 6250        // N_NODES*64/4/256 exactly
#define BSMAX 12032        // k_bsort LDS capacity (mean 8192 + 42 sigma)
#define NBANK 64           // BN accumulator banks (R14 lesson: spread the RMW chains)

typedef unsigned short u16;
typedef unsigned int u32;
typedef __attribute__((ext_vector_type(8))) short bf16x8;
typedef __attribute__((ext_vector_type(4))) float f32x4;
typedef __attribute__((ext_vector_type(2))) float f32x2;

__device__ __forceinline__ float bflo(u32 b) {
    u32 t = b << 16; return __builtin_bit_cast(float, t);
}
__device__ __forceinline__ float bfhi(u32 b) {
    u32 t = b & 0xffff0000u; return __builtin_bit_cast(float, t);
}
__device__ __forceinline__ f32x2 bfpair(u32 b) {
    return (f32x2){bflo(b), bfhi(b)};
}
__device__ __forceinline__ u16 f2bf(float f) {   // round-to-nearest-even
    u32 u = __builtin_bit_cast(u32, f);
    return (u16)((u + 0x7fffu + ((u >> 16) & 1u)) >> 16);
}

// ---------------- fused setup: cast | weight-prep+bank-zero | edge hist | gstart --------
__global__ void k_setup(const float* __restrict__ x, u16* __restrict__ xb,
                        const float* __restrict__ W10, const float* __restrict__ W20,
                        const float* __restrict__ W11, const float* __restrict__ W21,
                        const float* __restrict__ W12, const float* __restrict__ W22,
                        u16* __restrict__ Wtg, float* __restrict__ banks,
                        const int* __restrict__ dst, const int* __restrict__ batch,
                        int* __restrict__ blockhist, int* __restrict__ gstart,
                        int* __restrict__ rowstart) {
    __shared__ int hist[NBUCK];
    int b = blockIdx.x;
    int t = threadIdx.x;
    if (b < CAST_B) {
        int base = (b * 256 + t) * 4;
        float4 v = *(const float4*)(x + base);
        ushort4 o = make_ushort4(f2bf(v.x), f2bf(v.y), f2bf(v.z), f2bf(v.w));
        *(ushort4*)(xb + base) = o;
    } else if (b < CAST_B + 97) {
        int bb = b - CAST_B;
        if (bb < 96) {
            int e = bb * 256 + t;          // < 24576 = 6 * 4096
            int mat = e >> 12;
            int i = e & 4095;
            const float* s = (mat == 0) ? W10 : (mat == 1) ? W20 : (mat == 2) ? W11
                           : (mat == 3) ? W21 : (mat == 4) ? W12 : W22;
            float v = s[i];
            int k = i >> 6, c = i & 63;
            Wtg[mat * 4608 + c * 72 + k] = f2bf(v);
        } else {
            // zero all 4 layers' BN banks: 4*64*128 floats = 8192 uint4
            uint4 z = make_uint4(0, 0, 0, 0);
            for (int i = t; i < 8192; i += 256) ((uint4*)banks)[i] = z;
            if (t == 0) rowstart[N_NODES] = N_EDGES;
        }
    } else if (b < CAST_B + 97 + EB) {
        int be = b - (CAST_B + 97);
        long e0 = (long)be * CHUNK;
        for (int i = t; i < NBUCK; i += 256) hist[i] = 0;
        __syncthreads();
        for (int i = t; i < CHUNK; i += 256) {
            long e = e0 + i;
            if (e < N_EDGES) atomicAdd(&hist[dst[e] >> BSHIFT], 1);
        }
        __syncthreads();
        for (int i = t; i < NBUCK; i += 256) blockhist[be * NBUCK + i] = hist[i];
    } else {
        int i = (b - (CAST_B + 97 + EB)) * 256 + t;
        if (i < N_NODES) {
            int bi = batch[i];
            int bp = (i == 0) ? -1 : batch[i - 1];
            for (int g = bp + 1; g <= bi; ++g) gstart[g] = i;
            if (i == N_NODES - 1)
                for (int g = bi + 1; g <= NGRAPH; ++g) gstart[g] = N_NODES;
        }
    }
}

// one block per bucket k: exclusive-scan blockhist column k (in place) + total.
__global__ void k_scan_cols(int* __restrict__ blockhist, int* __restrict__ colsum) {
    __shared__ int sh[512];
    int k = blockIdx.x;
    int t = threadIdx.x;
    int v = (t < EB) ? blockhist[t * NBUCK + k] : 0;
    sh[t] = v;
    __syncthreads();
    for (int off = 1; off < 512; off <<= 1) {
        int x = (t >= off) ? sh[t - off] : 0;
        __syncthreads();
        sh[t] += x;
        __syncthreads();
    }
    if (t < EB) blockhist[t * NBUCK + k] = sh[t] - v;
    if (t == 511) colsum[k] = sh[511];
}

// LDS-staged bucket scatter. R18: the redundant per-chunk count pass (8192 dst
// reads + LDS atomics) is deleted -- own counts come from differencing the
// SCANNED blockhist rows (b+1 minus b; last chunk vs colsum). Block 0 publishes
// the bucket global starts (bstart_g) so k_bsort needn't redo the colsum scan.
__global__ __launch_bounds__(512) void k_bscatter(
    const int* __restrict__ src, const int* __restrict__ dst,
    const int* __restrict__ colsum, const int* __restrict__ blockhist,
    int* __restrict__ pairs, int* __restrict__ bstart_g) {
    __shared__ int sh[512];
    __shared__ int bstart_s[NBUCK];
    __shared__ int cur[NBUCK];
    __shared__ int gbase[NBUCK];
    __shared__ u32 sorted[CHUNK];
    __shared__ u16 kbuf[CHUNK];
    int t = threadIdx.x;
    int b = blockIdx.x;
    long e0 = (long)b * CHUNK;
    // issue all global reads up front (colsum + my blockhist row + next row)
    int v = (t < NBUCK) ? colsum[t] : 0;
    int myrow = (t < NBUCK) ? blockhist[b * NBUCK + t] : 0;
    int nxt = (t < NBUCK) ? ((b < EB - 1) ? blockhist[(b + 1) * NBUCK + t] : v) : 0;
    int own = nxt - myrow;                 // this chunk's count for bucket t
    sh[t] = v;
    __syncthreads();
    for (int off = 1; off < 512; off <<= 1) {
        int x = (t >= off) ? sh[t - off] : 0;
        __syncthreads();
        sh[t] += x;
        __syncthreads();
    }
    if (t < NBUCK) bstart_s[t] = sh[t] - v;
    if (b == 0) {
        if (t < NBUCK) bstart_g[t] = sh[t] - v;
        if (t == 0) bstart_g[NBUCK] = N_EDGES;
    }
    __syncthreads();
    sh[t] = (t < NBUCK) ? own : 0;
    __syncthreads();
    for (int off = 1; off < 512; off <<= 1) {
        int x = (t >= off) ? sh[t - off] : 0;
        __syncthreads();
        sh[t] += x;
        __syncthreads();
    }
    if (t < NBUCK) {
        int excl = sh[t] - own;
        cur[t] = excl;
        gbase[t] = bstart_s[t] + myrow - excl;
    }
    __syncthreads();
    for (int i = t; i < CHUNK; i += 512) {
        long e = e0 + i;
        if (e < N_EDGES) {
            int d = dst[e];
            int k = d >> BSHIFT;
            int r = atomicAdd(&cur[k], 1);
            sorted[r] = ((u32)src[e] << 8) | (u32)(d & 255);
            kbuf[r] = (u16)k;
        }
    }
    __syncthreads();
    int tot = (int)min((long)CHUNK, (long)N_EDGES - e0);
    for (int i = t; i < tot; i += 512)
        pairs[gbase[kbuf[i]] + i] = (int)sorted[i];
}

// per-bucket fine counting sort; LDS-staged output -> coalesced esrc writes.
// R18: bucket bounds come from bstart_g (two scalar loads) instead of a
// 20-barrier 512-wide colsum scan per block.
__global__ __launch_bounds__(512) void k_bsort(
    const int* __restrict__ pairs, const int* __restrict__ bstart_g,
    int* __restrict__ rowstart, int* __restrict__ esrc) {
    __shared__ int sh[256];
    __shared__ int deg[256];
    __shared__ int cur[256];
    __shared__ u32 ssrc[BSMAX];
    int b = blockIdx.x;
    int t = threadIdx.x;
    int p0 = bstart_g[b];
    int p1 = bstart_g[b + 1];
    int n = p1 - p0;
    if (t < 256) deg[t] = 0;
    __syncthreads();
    for (int i = p0 + t; i < p1; i += 512)
        atomicAdd(&deg[pairs[i] & 255], 1);
    __syncthreads();
    if (t < 256) sh[t] = deg[t];
    __syncthreads();
    for (int off = 1; off < 256; off <<= 1) {
        int x = (t >= off && t < 256) ? sh[t - off] : 0;
        __syncthreads();
        if (t < 256) sh[t] += x;
        __syncthreads();
    }
    if (t < 256) {
        int excl = sh[t] - deg[t];
        cur[t] = excl;
        int node = (b << BSHIFT) + t;
        if (node < N_NODES) rowstart[node] = p0 + excl;
    }
    __syncthreads();
    if (n <= BSMAX) {
        for (int i = p0 + t; i < p1; i += 512) {
            u32 pr = (u32)pairs[i];
            int r = atomicAdd(&cur[pr & 255], 1);
            ssrc[r] = pr >> 8;
        }
        __syncthreads();
        for (int i = t; i < n; i += 512) esrc[p0 + i] = (int)ssrc[i];
    } else {   // statistical impossibility; correctness fallback
        for (int i = p0 + t; i < p1; i += 512) {
            u32 pr = (u32)pairs[i];
            int r = atomicAdd(&cur[pr & 255], 1);
            esrc[p0 + r] = (int)(pr >> 8);
        }
    }
}

// ---------------- fused GIN layer: per-WAVE agg -> LDS -> MFMA ----------------
// Phase A/B VERBATIM R10 (proven; every restructuring lost). BN flows through
// NBANK=64 spread atomic banks (R17, proven):
//  - tail: wave (2*blk+wid)&63 atomicAdds psum/psq into its bank.
//  - prologue: 128 threads column-reduce the previous layer's 32KB bank region,
//    one barrier, per-thread scale/shift.
// Kernel-boundary visibility only; no fences (R13 lesson). No nt annotations
// (R19 lesson: nt on sub-line stores defeats L2 write-combining, +37% WRITE).
__global__ __launch_bounds__(128, 5) void k_fused(
    const u16* __restrict__ hin, const float* __restrict__ bank_in,
    const float* __restrict__ gbn, const float* __restrict__ bebn, int raw,
    const float* __restrict__ epsp, const int* __restrict__ rowstart,
    const int* __restrict__ esrc, const u16* __restrict__ Wt,
    const float* __restrict__ b1, const float* __restrict__ b2,
    u16* __restrict__ C, float* __restrict__ bank_out) {
    __shared__ __align__(16) u16 Ain[2][16 * 72];
    __shared__ __align__(16) u16 Hs[2][16 * 72];
    __shared__ float bnl[128];
    int tid = threadIdx.x;
    int lane = tid & 63;
    int wid = tid >> 6;
    int r0 = blockIdx.x * 32 + wid * 16;

    // ---- BN prologue: column-reduce banks -> LDS -> per-thread scale/shift ----
    if (!raw) {
        float s = 0.f;
        #pragma unroll 8
        for (int b = 0; b < NBANK; ++b) s += bank_in[b * 128 + tid];
        bnl[tid] = s;
    }
    __syncthreads();

    int grp = lane >> 3;
    int f0 = 8 * (lane & 7);
    float epsv = 1.0f + epsp[0];
    float sc[8], sh[8];
    if (raw) {
        #pragma unroll
        for (int k = 0; k < 8; ++k) { sc[k] = 1.0f; sh[k] = 0.0f; }
    } else {
        #pragma unroll
        for (int k = 0; k < 8; ++k) {
            int f = f0 + k;
            float S = bnl[f];
            float Q = bnl[64 + f];
            float mu = S * (1.0f / (float)N_NODES);
            float var = fmaxf(Q * (1.0f / (float)N_NODES) - mu * mu, 0.f);
            float s = gbn[f] * rsqrtf(var + BN_EPS);
            sc[k] = s;
            sh[k] = bebn[f] - mu * s;
        }
    }

    // ---- phase A: aggregate 16 nodes (R10 body) ----
    for (int t = 0; t < 16; ++t) {
        int node = r0 + t;
        u32* arow = (u32*)&Ain[wid][0] + t * 36 + (lane & 7) * 4;
        if (node < N_NODES) {
            f32x2 ac0 = {0.f, 0.f}, ac1 = {0.f, 0.f}, ac2 = {0.f, 0.f}, ac3 = {0.f, 0.f};
            int e0 = rowstart[node], e1 = rowstart[node + 1];
            for (int i = e0; i < e1; i += 64) {
                int cnt = min(e1 - i, 64);
                int src = (lane < cnt) ? esrc[i + lane] : 0;
                int j = 0;
                for (; j + 16 <= cnt; j += 16) {
                    int a = __shfl(src, j + grp);
                    int b = __shfl(src, j + 8 + grp);
                    uint4 va = *(const uint4*)(hin + (size_t)a * 64 + f0);
                    uint4 vb = *(const uint4*)(hin + (size_t)b * 64 + f0);
                    ac0 += bfpair(va.x); ac1 += bfpair(va.y);
                    ac2 += bfpair(va.z); ac3 += bfpair(va.w);
                    ac0 += bfpair(vb.x); ac1 += bfpair(vb.y);
                    ac2 += bfpair(vb.z); ac3 += bfpair(vb.w);
                }
                if (j + 8 <= cnt) {
                    int a = __shfl(src, j + grp);
                    uint4 va = *(const uint4*)(hin + (size_t)a * 64 + f0);
                    ac0 += bfpair(va.x); ac1 += bfpair(va.y);
                    ac2 += bfpair(va.z); ac3 += bfpair(va.w);
                    j += 8;
                }
                if (j < cnt) {   // clamp src (all lanes active), gate accumulate
                    int jj = j + grp;
                    int a = __shfl(src, (jj < cnt) ? jj : (cnt - 1));
                    uint4 va = *(const uint4*)(hin + (size_t)a * 64 + f0);
                    if (jj < cnt) {
                        ac0 += bfpair(va.x); ac1 += bfpair(va.y);
                        ac2 += bfpair(va.z); ac3 += bfpair(va.w);
                    }
                }
            }
            float acc[8] = {ac0.x, ac0.y, ac1.x, ac1.y, ac2.x, ac2.y, ac3.x, ac3.y};
            #pragma unroll
            for (int k = 0; k < 8; ++k) {
                acc[k] += __shfl_xor(acc[k], 8);
                acc[k] += __shfl_xor(acc[k], 16);
                acc[k] += __shfl_xor(acc[k], 32);
            }
            float deg = (float)(e1 - e0);
            uint4 sb = *(const uint4*)(hin + (size_t)node * 64 + f0);
            float self[8] = {bflo(sb.x), bfhi(sb.x), bflo(sb.y), bfhi(sb.y),
                             bflo(sb.z), bfhi(sb.z), bflo(sb.w), bfhi(sb.w)};
            if (grp == 0) {
                u32 pk[4];
                #pragma unroll
                for (int k = 0; k < 4; ++k) {
                    float oa = sc[2 * k] * (acc[2 * k] + epsv * self[2 * k]) +
                               (deg + epsv) * sh[2 * k];
                    float ob = sc[2 * k + 1] * (acc[2 * k + 1] + epsv * self[2 * k + 1]) +
                               (deg + epsv) * sh[2 * k + 1];
                    pk[k] = (u32)f2bf(oa) | ((u32)f2bf(ob) << 16);
                }
                *(uint4*)arow = make_uint4(pk[0], pk[1], pk[2], pk[3]);
            }
        } else if (grp == 0) {
            *(uint4*)arow = make_uint4(0, 0, 0, 0);
        }
    }
    // no barrier: phase B reads only this wave's Ain tile (in-order DS per wave)

    // ---- phase B: MFMA MLP on the wave's 16-row tile ----
    const u16* Wt2 = Wt + 4608;
    int m = lane & 15;
    int q = lane >> 4;

    bf16x8 a0 = *(const bf16x8*)(&Ain[wid][m * 72 + q * 8]);
    bf16x8 a1 = *(const bf16x8*)(&Ain[wid][m * 72 + 32 + q * 8]);
    f32x4 acc[4];
    #pragma unroll
    for (int c = 0; c < 4; ++c) {
        acc[c] = (f32x4){0.f, 0.f, 0.f, 0.f};
        bf16x8 bA = *(const bf16x8*)(Wt + (c * 16 + m) * 72 + q * 8);
        bf16x8 bB = *(const bf16x8*)(Wt + (c * 16 + m) * 72 + 32 + q * 8);
        acc[c] = __builtin_amdgcn_mfma_f32_16x16x32_bf16(a0, bA, acc[c], 0, 0, 0);
        acc[c] = __builtin_amdgcn_mfma_f32_16x16x32_bf16(a1, bB, acc[c], 0, 0, 0);
    }
    #pragma unroll
    for (int c = 0; c < 4; ++c) {
        int col = c * 16 + m;
        float bb = b1[col];
        #pragma unroll
        for (int r = 0; r < 4; ++r)
            Hs[wid][(q * 4 + r) * 72 + col] = f2bf(fmaxf(acc[c][r] + bb, 0.f));
    }
    bf16x8 h0 = *(const bf16x8*)(&Hs[wid][m * 72 + q * 8]);
    bf16x8 h1 = *(const bf16x8*)(&Hs[wid][m * 72 + 32 + q * 8]);
    f32x4 acc2[4];
    #pragma unroll
    for (int c = 0; c < 4; ++c) {
        acc2[c] = (f32x4){0.f, 0.f, 0.f, 0.f};
        bf16x8 bA = *(const bf16x8*)(Wt2 + (c * 16 + m) * 72 + q * 8);
        bf16x8 bB = *(const bf16x8*)(Wt2 + (c * 16 + m) * 72 + 32 + q * 8);
        acc2[c] = __builtin_amdgcn_mfma_f32_16x16x32_bf16(h0, bA, acc2[c], 0, 0, 0);
        acc2[c] = __builtin_amdgcn_mfma_f32_16x16x32_bf16(h1, bB, acc2[c], 0, 0, 0);
    }
    float* bo = bank_out + (size_t)(((blockIdx.x << 1) | wid) & (NBANK - 1)) * 128;
    #pragma unroll
    for (int c = 0; c < 4; ++c) {
        int col = c * 16 + m;
        float bb = b2[col];
        float psum = 0.f, psq = 0.f;
        #pragma unroll
        for (int r = 0; r < 4; ++r) {
            int rg = r0 + q * 4 + r;
            if (rg < N_NODES) {
                float o = fmaxf(acc2[c][r] + bb, 0.f);
                C[(size_t)rg * 64 + col] = f2bf(o);
                psum += o;
                psq += o * o;
            }
        }
        psum += __shfl_xor(psum, 16);
        psum += __shfl_xor(psum, 32);
        psq += __shfl_xor(psq, 16);
        psq += __shfl_xor(psq, 32);
        if (q == 0) {
            atomicAdd(&bo[col], psum);          // fire-and-forget, spread banks
            atomicAdd(&bo[64 + col], psq);
        }
    }
}

// ---------------- pooling + FC + log_softmax ----------------
__global__ void k_pool(const u16* __restrict__ h, const float* __restrict__ bank_in,
                       const float* __restrict__ gbn, const float* __restrict__ bebn,
                       const int* __restrict__ gstart, const float* __restrict__ wfc,
                       const float* __restrict__ bfc, float* __restrict__ out) {
    __shared__ float smean[2][128];
    __shared__ float smax[2][128];
    __shared__ float lg[2][8];
    __shared__ float bnl[128];
    int tid = threadIdx.x;
    int lane = tid & 63;
    int w = tid >> 6;
    int gi = w >> 1;
    int part = w & 1;
    int gr = blockIdx.x * 2 + gi;
    int half = lane >> 5;
    int li = lane & 31;
    int f0 = 2 * li;

    if (tid < 128) {
        float s = 0.f;
        #pragma unroll 8
        for (int b = 0; b < NBANK; ++b) s += bank_in[b * 128 + tid];
        bnl[tid] = s;
    }
    __syncthreads();
    float sc0, sc1, sh0, sh1;
    {
        float S0 = bnl[f0], Q0 = bnl[64 + f0];
        float S1 = bnl[f0 + 1], Q1 = bnl[64 + f0 + 1];
        float mu0 = S0 * (1.0f / (float)N_NODES);
        float mu1 = S1 * (1.0f / (float)N_NODES);
        float v0 = fmaxf(Q0 * (1.0f / (float)N_NODES) - mu0 * mu0, 0.f);
        float v1 = fmaxf(Q1 * (1.0f / (float)N_NODES) - mu1 * mu1, 0.f);
        sc0 = gbn[f0] * rsqrtf(v0 + BN_EPS);
        sc1 = gbn[f0 + 1] * rsqrtf(v1 + BN_EPS);
        sh0 = bebn[f0] - mu0 * sc0;
        sh1 = bebn[f0 + 1] - mu1 * sc1;
    }
    int s0n = gstart[gr], s1n = gstart[gr + 1];
    int cnt = s1n - s0n;
    int mid = s0n + (cnt >> 1);
    int a = part ? mid : s0n;
    int b = part ? s1n : mid;
    float sum0 = 0.f, sum1 = 0.f, mx0 = -3.4e38f, mx1 = -3.4e38f;
    for (int n = a + half; n < b; n += 2) {
        u32 bits = *(const u32*)(h + (size_t)n * 64 + f0);
        float x0 = fmaf(bflo(bits), sc0, sh0);
        float x1 = fmaf(bfhi(bits), sc1, sh1);
        sum0 += x0; sum1 += x1;
        mx0 = fmaxf(mx0, x0); mx1 = fmaxf(mx1, x1);
    }
    sum0 += __shfl_xor(sum0, 32);
    sum1 += __shfl_xor(sum1, 32);
    mx0 = fmaxf(mx0, __shfl_xor(mx0, 32));
    mx1 = fmaxf(mx1, __shfl_xor(mx1, 32));
    if (half == 0 && part == 0) {
        smean[gi][f0] = sum0; smean[gi][f0 + 1] = sum1;
        smax[gi][f0] = mx0;   smax[gi][f0 + 1] = mx1;
    }
    __syncthreads();
    if (half == 0 && part == 1) {
        float m0 = fmaxf(smax[gi][f0], mx0), m1 = fmaxf(smax[gi][f0 + 1], mx1);
        float t0 = smean[gi][f0] + sum0, t1 = smean[gi][f0 + 1] + sum1;
        float fc = fmaxf((float)cnt, 1.f);
        smean[gi][f0] = t0 / fc;
        smean[gi][f0 + 1] = t1 / fc;
        smax[gi][f0] = (cnt > 0) ? m0 : 0.f;
        smax[gi][f0 + 1] = (cnt > 0) ? m1 : 0.f;
    }
    __syncthreads();
    if (part == 0 && lane < NCLASS) {
        float acc = bfc[lane];
        for (int j = 0; j < 64; ++j) acc = fmaf(smean[gi][j], wfc[j * NCLASS + lane], acc);
        for (int j = 0; j < 64; ++j) acc = fmaf(smax[gi][j], wfc[(64 + j) * NCLASS + lane], acc);
        lg[gi][lane] = acc;
    }
    __syncthreads();
    if (part == 0 && lane < NCLASS) {
        float mm = -3.4e38f;
        for (int c = 0; c < NCLASS; ++c) mm = fmaxf(mm, lg[gi][c]);
        float se = 0.f;
        for (int c = 0; c < NCLASS; ++c) se += expf(lg[gi][c] - mm);
        out[gr * NCLASS + lane] = lg[gi][lane] - mm - logf(se);
    }
}

// ---------------- launch ----------------

extern "C" void kernel_launch(void* const* d_in, const int* in_sizes, int n_in,
                              void* d_out, int out_size, void* d_ws, size_t ws_size,
                              hipStream_t stream) {
    const float* x = (const float*)d_in[0];
    const int* ei = (const int*)d_in[1];
    const int* batch = (const int*)d_in[2];
    const int* esrc_in = ei;
    const int* edst_in = ei + N_EDGES;

    const float* ba[4] = {(const float*)d_in[4], (const float*)d_in[8],
                          (const float*)d_in[12], (const float*)d_in[12]};
    const float* bb[4] = {(const float*)d_in[6], (const float*)d_in[10],
                          (const float*)d_in[14], (const float*)d_in[14]};
    const float* epsv[4] = {(const float*)d_in[15], (const float*)d_in[18],
                            (const float*)d_in[21], (const float*)d_in[24]};
    const float* gg[4] = {(const float*)d_in[16], (const float*)d_in[19],
                          (const float*)d_in[22], (const float*)d_in[25]};
    const float* bee[4] = {(const float*)d_in[17], (const float*)d_in[20],
                           (const float*)d_in[23], (const float*)d_in[26]};
    const float* wfc = (const float*)d_in[27];
    const float* bfc = (const float*)d_in[28];
    float* out = (float*)d_out;

    char* ws = (char*)d_ws;
    int* pairs = (int*)(ws + 0);               // 12,800,000 (dead after k_bsort)
    u16* bufA = (u16*)(ws + 0);                // alias of pairs (first write: L1)
    int* esrc = (int*)(ws + 12800000);         // 12,800,000
    u16* xb = (u16*)(ws + 25600000);           // 12,800,000
    u16* bufB = (u16*)(ws + 38400000);         // 12,800,000
    int* rowstart = (int*)(ws + 51200000);     // 400,128
    int* blockhist = (int*)(ws + 51600128);    // 612,352 (padded)
    int* colsum = (int*)(ws + 52212480);       // 2,048
    int* gstart = (int*)(ws + 52214528);       // 2,560
    float* banks = (float*)(ws + 52217088);    // 4 layers x 64 banks x 128 f32 = 131,072
    u16* Wtg = (u16*)(ws + 52348160);          // 55,296
    int* bstart_g = (int*)(ws + 52403456);     // 392 ints -> 2,048
    // total: 52,405,504 bytes; no memsets needed

    k_setup<<<CAST_B + 97 + EB + NBLK_NODE, 256, 0, stream>>>(
        x, xb, (const float*)d_in[3], (const float*)d_in[5], (const float*)d_in[7],
        (const float*)d_in[9], (const float*)d_in[11], (const float*)d_in[13],
        Wtg, banks, edst_in, batch, blockhist, gstart, rowstart);
    k_scan_cols<<<NBUCK, 512, 0, stream>>>(blockhist, colsum);
    k_bscatter<<<EB, 512, 0, stream>>>(esrc_in, edst_in, colsum, blockhist, pairs,
                                       bstart_g);
    k_bsort<<<NBUCK, 512, 0, stream>>>(pairs, bstart_g, rowstart, esrc);

    // ping-pong: L0 xb->B, L1 B->A, L2 A->B, L3 B->A; pool reads A
    const u16* hb[4] = {xb, bufB, bufA, bufB};
    u16* cb[4] = {bufB, bufA, bufB, bufA};
    for (int L = 0; L < 4; ++L) {
        const u16* wt = Wtg + (size_t)((L < 2) ? L : 2) * 9216;
        const float* bin = (L == 0) ? banks : banks + (size_t)(L - 1) * NBANK * 128;
        const float* gprev = (L == 0) ? gg[0] : gg[L - 1];
        const float* beprev = (L == 0) ? bee[0] : bee[L - 1];
        k_fused<<<FUSG, 128, 0, stream>>>(hb[L], bin, gprev, beprev, (L == 0) ? 1 : 0,
                                          epsv[L], rowstart, esrc, wt, ba[L], bb[L],
                                          cb[L], banks + (size_t)L * NBANK * 128);
    }

    k_pool<<<NGRAPH / 2, 256, 0, stream>>>(bufA, banks + (size_t)3 * NBANK * 128,
                                           gg[3], bee[3], gstart, wfc, bfc, out);
}